// Round 2
// baseline (3313.642 us; speedup 1.0000x reference)
//
#include <hip/hip_runtime.h>

#define HDIM 64
#define NMODE 5
#define TOUT 6
#define TIN 5
#define NNODE 5
#define FD 10
#define SPW 12      // samples per wave (12*5 = 60 active lanes of 64)
#define ACT 60

// ---------------- ws layout (floats) ----------------
// 0      : WcE[10][192]   = embed_W @ enc_Wih^T        (folded encoder input weights)
// 1920   : bcE[192]       = embed_b @ enc_Wih^T + enc_bih
// 2112   : WcD[2][192]    = proj_W @ dec_Wih^T
// 2496   : bcD[192]       = proj_b @ dec_Wih^T + dec_bih
// 2688   : W1T[64][64]    = out_W1 transposed  (W1T[a][k] = out_W1[k][a])
// 6784   : cW1T[64][64]   = conf_W1 transposed
// 10880  : gWT[64][64]    = gat_W transposed   (gWT[r][e] = gat_W[e][r])
// 14976  : embWT[64][10]  = embed_W transposed (embWT[e][f] = embed_W[f][e])
// 15616  : brzE[128]      = bcE[0:128] + enc_bhh[0:128]   (folded r/z bias)
// 15744  : brzD[128]      = bcD[0:128] + dec_bhh[0:128]
// 15872  : end

__device__ __forceinline__ float fastrcp(float x){ return __builtin_amdgcn_rcpf(x); }
__device__ __forceinline__ float sigm(float x){ return fastrcp(1.f + __expf(-x)); }
__device__ __forceinline__ float tanh_f(float x){ return 2.f*fastrcp(1.f + __expf(-2.f*x)) - 1.f; }

__global__ void setup_kernel(const float* __restrict__ embed_W, const float* __restrict__ embed_b,
                             const float* __restrict__ enc_Wih, const float* __restrict__ enc_bih,
                             const float* __restrict__ dec_Wih, const float* __restrict__ dec_bih,
                             const float* __restrict__ proj_W,  const float* __restrict__ proj_b,
                             const float* __restrict__ out_W1,  const float* __restrict__ conf_W1,
                             const float* __restrict__ gat_W,
                             const float* __restrict__ enc_bhh, const float* __restrict__ dec_bhh,
                             float* __restrict__ ws)
{
  const int t = threadIdx.x;
  for (int idx = t; idx < 1920; idx += 256){           // WcE[f][row]
    int f = idx / 192, row = idx % 192;
    float s = 0.f;
    for (int e = 0; e < HDIM; e++) s += embed_W[f*HDIM+e]*enc_Wih[row*HDIM+e];
    ws[idx] = s;
  }
  for (int row = t; row < 192; row += 256){            // bcE
    float s = enc_bih[row];
    for (int e = 0; e < HDIM; e++) s += embed_b[e]*enc_Wih[row*HDIM+e];
    ws[1920+row] = s;
  }
  for (int idx = t; idx < 384; idx += 256){            // WcD[c][row]
    int c = idx / 192, row = idx % 192;
    float s = 0.f;
    for (int e = 0; e < HDIM; e++) s += proj_W[c*HDIM+e]*dec_Wih[row*HDIM+e];
    ws[2112+idx] = s;
  }
  for (int row = t; row < 192; row += 256){            // bcD
    float s = dec_bih[row];
    for (int e = 0; e < HDIM; e++) s += proj_b[e]*dec_Wih[row*HDIM+e];
    ws[2496+row] = s;
  }
  for (int idx = t; idx < 4096; idx += 256){           // transposes
    int a = idx >> 6, k = idx & 63;
    ws[2688 + idx]  = out_W1 [k*HDIM + a];
    ws[6784 + idx]  = conf_W1[k*HDIM + a];
    ws[10880 + idx] = gat_W  [k*HDIM + a];
  }
  for (int idx = t; idx < 640; idx += 256){            // embWT[e][f]
    int e = idx / FD, f = idx % FD;
    ws[14976 + idx] = embed_W[f*HDIM + e];
  }
  for (int row = t; row < 128; row += 256){            // brzE / brzD (recompute bc, fold bhh)
    float sE = enc_bih[row], sD = dec_bih[row];
    for (int e = 0; e < HDIM; e++){
      sE += embed_b[e]*enc_Wih[row*HDIM+e];
      sD += proj_b[e]*dec_Wih[row*HDIM+e];
    }
    ws[15616+row] = sE + enc_bhh[row];
    ws[15744+row] = sD + dec_bhh[row];
  }
}

// One GRU step. Invariant: on entry lds[k][lane] == h[k]; on exit same (new h).
// Weights indexed uniformly -> scalar loads; h lives in VGPRs (k-loops unrolled).
// lds columns are lane-private here (no cross-lane traffic) -> no barrier needed;
// wave_barrier only pins instruction order (block = 1 wave).
template<int NX>
__device__ __forceinline__ void gru_step(float* __restrict__ h, const float* __restrict__ xv,
    const float* __restrict__ Wc,  const float* __restrict__ brz,
    const float* __restrict__ bni, const float* __restrict__ bnh,
    const float* __restrict__ Whh, int lane, float (*lds)[64])
{
  #pragma unroll 4
  for (int hi = 0; hi < HDIM; hi++){
    float ar  = brz[hi];
    float az  = brz[HDIM+hi];
    float ani = bni[hi];
    float anh = bnh[hi];
    #pragma unroll
    for (int f = 0; f < NX; f++){
      ar  += xv[f]*Wc[f*192 + hi];
      az  += xv[f]*Wc[f*192 + HDIM + hi];
      ani += xv[f]*Wc[f*192 + 2*HDIM + hi];
    }
    const float* wr = Whh + hi*HDIM;
    const float* wz = Whh + (HDIM+hi)*HDIM;
    const float* wn = Whh + (2*HDIM+hi)*HDIM;
    float dr0=0.f, dr1=0.f, dz0=0.f, dz1=0.f, dn0=0.f, dn1=0.f;
    #pragma unroll
    for (int k = 0; k < 32; k++){
      dr0 += h[k]*wr[k];      dr1 += h[k+32]*wr[k+32];
      dz0 += h[k]*wz[k];      dz1 += h[k+32]*wz[k+32];
      dn0 += h[k]*wn[k];      dn1 += h[k+32]*wn[k+32];
    }
    float r = sigm(ar + dr0 + dr1);
    float z = sigm(az + dz0 + dz1);
    float n = tanh_f(ani + r*(anh + dn0 + dn1));
    float hold = lds[hi][lane];            // == old h[hi], avoids dynamic reg index
    lds[hi][lane] = (1.f - z)*n + z*hold;
  }
  __builtin_amdgcn_wave_barrier();
  #pragma unroll
  for (int k = 0; k < HDIM; k++) h[k] = lds[k][lane];
  __builtin_amdgcn_wave_barrier();
}

__global__ __launch_bounds__(64) void model_kernel(
    const float* __restrict__ x,
    const float* __restrict__ ws,
    const float* __restrict__ enc_Whh, const float* __restrict__ enc_bhh,
    const float* __restrict__ dec_Whh, const float* __restrict__ dec_bhh,
    const float* __restrict__ embed_b,
    const float* __restrict__ gat_att_src, const float* __restrict__ gat_att_dst,
    const float* __restrict__ gat_b,
    const float* __restrict__ out_b1, const float* __restrict__ out_W2, const float* __restrict__ out_b2,
    const float* __restrict__ conf_b1, const float* __restrict__ conf_W2, const float* __restrict__ conf_b2,
    float* __restrict__ traj_out, float* __restrict__ conf_out,
    int B)
{
  __shared__ float lds[HDIM][64];   // transposed [idx][lane]: conflict-free everywhere
  const int lane = threadIdx.x;
  const int sl = lane / 5;
  const int nl = lane - sl*5;
  const int samp = blockIdx.x*SPW + sl;
  const bool active = (lane < ACT) && (samp < B);
  const int sc = (samp < B) ? samp : (B-1);
  const float* xb = x + (size_t)sc*(TIN*NNODE*FD) + nl*FD;

  const float* WcE   = ws;
  const float* bcE   = ws + 1920;
  const float* WcD   = ws + 2112;
  const float* bcD   = ws + 2496;
  const float* W1T   = ws + 2688;
  const float* cW1T  = ws + 6784;
  const float* gWT   = ws + 10880;
  const float* embWT = ws + 14976;
  const float* brzE  = ws + 15616;
  const float* brzD  = ws + 15744;

  float h[HDIM];
  #pragma unroll
  for (int k = 0; k < HDIM; k++){ h[k] = 0.f; lds[k][lane] = 0.f; }
  __builtin_amdgcn_wave_barrier();

  // ---------------- GRU encoder (5 steps, x prefetched one step ahead) ---
  float xv[FD], xn[FD];
  #pragma unroll
  for (int f = 0; f < FD; f += 2){ float2 v = *(const float2*)(xb+f); xv[f] = v.x; xv[f+1] = v.y; }
  for (int t = 0; t < TIN; t++){
    if (t < TIN-1){
      const float* xt = xb + (t+1)*(NNODE*FD);
      #pragma unroll
      for (int f = 0; f < FD; f += 2){ float2 v = *(const float2*)(xt+f); xn[f] = v.x; xn[f+1] = v.y; }
    }
    gru_step<FD>(h, xv, WcE, brzE, bcE+2*HDIM, enc_bhh+2*HDIM, enc_Whh, lane, lds);
    #pragma unroll
    for (int f = 0; f < FD; f++) xv[f] = xn[f];
  }
  // restore xv = last frame (the loop clobbered it with garbage after t=4)
  {
    const float* xt = xb + (TIN-1)*(NNODE*FD);
    #pragma unroll
    for (int f = 0; f < FD; f += 2){ float2 v = *(const float2*)(xt+f); xv[f] = v.x; xv[f+1] = v.y; }
  }

  // ---------------- GAT on last frame ----------------
  float msum = 0.f;
  #pragma unroll
  for (int f = 0; f < 6; f++) msum += xv[f];
  const float maskf = (msum != 0.f) ? 1.f : 0.f;

  float emb[HDIM];                         // x_emb last frame (real embed, not folded)
  #pragma unroll 4
  for (int e = 0; e < HDIM; e++){
    float s = embed_b[e];
    #pragma unroll
    for (int f = 0; f < FD; f++) s += xv[f]*embWT[e*FD+f];
    emb[e] = s;
  }

  float asum = 0.f, adsum = 0.f;
  #pragma unroll 2
  for (int r = 0; r < HDIM; r++){          // xl = emb @ gat_W  -> lds; + attention dots
    float s0 = 0.f, s1 = 0.f;
    #pragma unroll
    for (int e = 0; e < 32; e++){ s0 += emb[e]*gWT[r*HDIM+e]; s1 += emb[e+32]*gWT[r*HDIM+e+32]; }
    float s = s0 + s1;
    lds[r][lane] = s;
    asum  += s*gat_att_src[r];
    adsum += s*gat_att_dst[r];
  }
  __syncthreads();                         // cross-lane exchange below

  const int base = ((sl <= 11) ? sl : 11)*5;   // clamp idle lanes in-bounds
  float as_i[5], mk_i[5];
  #pragma unroll
  for (int i = 0; i < 5; i++){
    as_i[i] = __shfl(asum,  base+i, 64);
    mk_i[i] = __shfl(maskf, base+i, 64);
  }
  float mx = -1e30f; float al[5];
  #pragma unroll
  for (int i = 0; i < 5; i++){
    float a = as_i[i] + adsum;
    a = (a > 0.f) ? a : 0.2f*a;                       // leaky_relu 0.2
    bool valid = (i == nl) || (mk_i[i] != 0.f && maskf != 0.f);
    al[i] = valid ? a : -1e30f;
    mx = fmaxf(mx, al[i]);
  }
  float w5[5]; float esum = 0.f;
  #pragma unroll
  for (int i = 0; i < 5; i++){
    float e = (al[i] > -1e29f) ? __expf(al[i]-mx) : 0.f;
    w5[i] = e; esum += e;
  }
  const float rs = fastrcp(esum);
  #pragma unroll
  for (int i = 0; i < 5; i++) w5[i] *= rs;

  #pragma unroll
  for (int k = 0; k < HDIM; k++){                      // h_final = h_enc + gat_out
    float agg = gat_b[k];
    #pragma unroll
    for (int i = 0; i < 5; i++) agg += w5[i]*lds[k][base+i];
    h[k] += agg;
  }
  __syncthreads();                                     // all neighbor reads done
  #pragma unroll
  for (int k = 0; k < HDIM; k++) lds[k][lane] = h[k];  // restore invariant for decoder
  __builtin_amdgcn_wave_barrier();

  // ---------------- confidence head ----------------
  float lg[NMODE];
  #pragma unroll
  for (int m = 0; m < NMODE; m++) lg[m] = conf_b2[m];
  #pragma unroll 4
  for (int ci = 0; ci < HDIM; ci++){
    float s0 = conf_b1[ci], s1 = 0.f;
    #pragma unroll
    for (int k = 0; k < 32; k++){ s0 += h[k]*cW1T[ci*HDIM+k]; s1 += h[k+32]*cW1T[ci*HDIM+k+32]; }
    float s = fmaxf(s0+s1, 0.f);
    #pragma unroll
    for (int m = 0; m < NMODE; m++) lg[m] += s*conf_W2[ci*NMODE+m];
  }
  float cm = lg[0];
  #pragma unroll
  for (int m = 1; m < NMODE; m++) cm = fmaxf(cm, lg[m]);
  float ce = 0.f;
  #pragma unroll
  for (int m = 0; m < NMODE; m++){ lg[m] = __expf(lg[m]-cm); ce += lg[m]; }
  const float rc = fastrcp(ce);
  if (active){
    #pragma unroll
    for (int m = 0; m < NMODE; m++)
      conf_out[((size_t)samp*NMODE + m)*NNODE + nl] = lg[m]*rc;
  }

  // ---------------- GRUCell decoder (6 steps) ----------------
  float xy[2] = { xv[0], xv[1] };                      // x[:, -1, :, 0:2]
  for (int t = 0; t < TOUT; t++){
    gru_step<2>(h, xy, WcD, brzD, bcD+2*HDIM, dec_bhh+2*HDIM, dec_Whh, lane, lds);

    float o[10];
    #pragma unroll
    for (int oi = 0; oi < 10; oi++) o[oi] = out_b2[oi];
    #pragma unroll 4
    for (int ai = 0; ai < HDIM; ai++){
      float s0 = out_b1[ai], s1 = 0.f;
      #pragma unroll
      for (int k = 0; k < 32; k++){ s0 += h[k]*W1T[ai*HDIM+k]; s1 += h[k+32]*W1T[ai*HDIM+k+32]; }
      float s = fmaxf(s0+s1, 0.f);
      #pragma unroll
      for (int oi = 0; oi < 10; oi++) o[oi] += s*out_W2[ai*10+oi];
    }
    if (active){
      #pragma unroll
      for (int m = 0; m < NMODE; m++){
        float2 st = { o[m], o[NMODE+m] };              // (x=o[..,0,m], y=o[..,1,m])
        *(float2*)&traj_out[(((size_t)samp*NMODE + m)*NNODE + nl)*(TOUT*2) + t*2] = st;
      }
    }
    xy[0] = o[0]; xy[1] = o[NMODE];                    // mode-0 xy fed back
  }
}

extern "C" void kernel_launch(void* const* d_in, const int* in_sizes, int n_in,
                              void* d_out, int out_size, void* d_ws, size_t ws_size,
                              hipStream_t stream)
{
  const float* x           = (const float*)d_in[0];
  const float* embed_W     = (const float*)d_in[1];
  const float* embed_b     = (const float*)d_in[2];
  const float* gat_W       = (const float*)d_in[3];
  const float* gat_att_src = (const float*)d_in[4];
  const float* gat_att_dst = (const float*)d_in[5];
  const float* gat_b       = (const float*)d_in[6];
  const float* enc_Wih     = (const float*)d_in[7];
  const float* enc_Whh     = (const float*)d_in[8];
  const float* enc_bih     = (const float*)d_in[9];
  const float* enc_bhh     = (const float*)d_in[10];
  const float* dec_Wih     = (const float*)d_in[11];
  const float* dec_Whh     = (const float*)d_in[12];
  const float* dec_bih     = (const float*)d_in[13];
  const float* dec_bhh     = (const float*)d_in[14];
  const float* out_W1      = (const float*)d_in[15];
  const float* out_b1      = (const float*)d_in[16];
  const float* out_W2      = (const float*)d_in[17];
  const float* out_b2      = (const float*)d_in[18];
  const float* proj_W      = (const float*)d_in[19];
  const float* proj_b      = (const float*)d_in[20];
  const float* conf_W1     = (const float*)d_in[21];
  const float* conf_b1     = (const float*)d_in[22];
  const float* conf_W2     = (const float*)d_in[23];
  const float* conf_b2     = (const float*)d_in[24];

  const int B = in_sizes[0] / (TIN*NNODE*FD);
  float* ws = (float*)d_ws;
  float* traj = (float*)d_out;
  float* conf = traj + (size_t)B*NMODE*NNODE*TOUT*2;

  setup_kernel<<<1, 256, 0, stream>>>(embed_W, embed_b, enc_Wih, enc_bih, dec_Wih, dec_bih,
                                      proj_W, proj_b, out_W1, conf_W1, gat_W,
                                      enc_bhh, dec_bhh, ws);

  const int blocks = (B + SPW - 1) / SPW;
  model_kernel<<<blocks, 64, 0, stream>>>(x, ws,
      enc_Whh, enc_bhh, dec_Whh, dec_bhh,
      embed_b, gat_att_src, gat_att_dst, gat_b,
      out_b1, out_W2, out_b2, conf_b1, conf_W2, conf_b2,
      traj, conf, B);
}

// Round 4
// 1948.969 us; speedup vs baseline: 1.7002x; 1.7002x over previous
//
#include <hip/hip_runtime.h>

#define HDIM 64
#define NMODE 5
#define TOUT 6
#define TIN 5
#define NNODE 5
#define FD 10
#define SPW 12      // samples per wave (12*5 = 60 active lanes of 64)
#define ACT 60

typedef float v2f __attribute__((ext_vector_type(2)));

// ---------------- ws layout (floats) ----------------
// 0      : WcET[192][10]  = folded encoder input weights, row-major per gate-row
//                           WcET[r][f] = sum_e embed_W[f][e]*enc_Wih[r][e]
// 1920   : bcE[192]       = embed_b @ enc_Wih^T + enc_bih
// 2112   : WcDT[192][2]   = WcDT[r][c] = sum_e proj_W[c][e]*dec_Wih[r][e]
// 2496   : bcD[192]       = proj_b @ dec_Wih^T + dec_bih
// 2688   : W1T[64][64]    = out_W1 transposed  (W1T[a][k] = out_W1[k][a])
// 6784   : cW1T[64][64]   = conf_W1 transposed
// 10880  : gWT[64][64]    = gat_W transposed   (gWT[r][e] = gat_W[e][r])
// 14976  : embWT[64][10]  = embed_W transposed (embWT[e][f] = embed_W[f][e])
// 15616  : brzE[128]      = bcE[0:128] + enc_bhh[0:128]   (folded r/z bias)
// 15744  : brzD[128]      = bcD[0:128] + dec_bhh[0:128]
// 15872  : end

__device__ __forceinline__ float fastrcp(float x){ return __builtin_amdgcn_rcpf(x); }
__device__ __forceinline__ float sigm(float x){ return fastrcp(1.f + __expf(-x)); }
__device__ __forceinline__ float tanh_f(float x){ return 2.f*fastrcp(1.f + __expf(-2.f*x)) - 1.f; }

__global__ void setup_kernel(const float* __restrict__ embed_W, const float* __restrict__ embed_b,
                             const float* __restrict__ enc_Wih, const float* __restrict__ enc_bih,
                             const float* __restrict__ dec_Wih, const float* __restrict__ dec_bih,
                             const float* __restrict__ proj_W,  const float* __restrict__ proj_b,
                             const float* __restrict__ out_W1,  const float* __restrict__ conf_W1,
                             const float* __restrict__ gat_W,
                             const float* __restrict__ enc_bhh, const float* __restrict__ dec_bhh,
                             float* __restrict__ ws)
{
  const int t = threadIdx.x;
  for (int idx = t; idx < 1920; idx += 256){           // WcET[r][f]
    int r = idx / FD, f = idx % FD;
    float s = 0.f;
    for (int e = 0; e < HDIM; e++) s += embed_W[f*HDIM+e]*enc_Wih[r*HDIM+e];
    ws[idx] = s;
  }
  for (int row = t; row < 192; row += 256){            // bcE
    float s = enc_bih[row];
    for (int e = 0; e < HDIM; e++) s += embed_b[e]*enc_Wih[row*HDIM+e];
    ws[1920+row] = s;
  }
  for (int idx = t; idx < 384; idx += 256){            // WcDT[r][c]
    int r = idx / 2, c = idx % 2;
    float s = 0.f;
    for (int e = 0; e < HDIM; e++) s += proj_W[c*HDIM+e]*dec_Wih[r*HDIM+e];
    ws[2112+idx] = s;
  }
  for (int row = t; row < 192; row += 256){            // bcD
    float s = dec_bih[row];
    for (int e = 0; e < HDIM; e++) s += proj_b[e]*dec_Wih[row*HDIM+e];
    ws[2496+row] = s;
  }
  for (int idx = t; idx < 4096; idx += 256){           // transposes
    int a = idx >> 6, k = idx & 63;
    ws[2688 + idx]  = out_W1 [k*HDIM + a];
    ws[6784 + idx]  = conf_W1[k*HDIM + a];
    ws[10880 + idx] = gat_W  [k*HDIM + a];
  }
  for (int idx = t; idx < 640; idx += 256){            // embWT[e][f]
    int e = idx / FD, f = idx % FD;
    ws[14976 + idx] = embed_W[f*HDIM + e];
  }
  for (int row = t; row < 128; row += 256){            // brzE / brzD
    float sE = enc_bih[row], sD = dec_bih[row];
    for (int e = 0; e < HDIM; e++){
      sE += embed_b[e]*enc_Wih[row*HDIM+e];
      sD += proj_b[e]*dec_Wih[row*HDIM+e];
    }
    ws[15616+row] = sE + enc_bhh[row];
    ws[15744+row] = sD + dec_bhh[row];
  }
}

// One GRU step. Invariant: on entry lds[k][lane] == h[k]; on exit same (new h).
// Weights uniform -> s_load + v_pk_fma_f32 (packed fp32, 2 MACs/issue).
// NXV = number of float2 x-elements (5 for encoder, 1 for decoder).
// NOTE: n-gate keeps SEPARATE accumulators: n = tanh(i_n + r*h_n) — the x-part
// (dni) must not be scaled by r. Merging them was round-3's correctness bug.
template<int NXV>
__device__ __forceinline__ void gru_step(v2f* __restrict__ h2, const v2f* __restrict__ xv2,
    const float* __restrict__ WcT, const float* __restrict__ brz,
    const float* __restrict__ bni, const float* __restrict__ bnh,
    const float* __restrict__ Whh, int lane, float (*lds)[64])
{
  for (int hi = 0; hi < HDIM; hi++){
    const v2f* wxr = (const v2f*)(WcT + hi*(2*NXV));
    const v2f* wxz = (const v2f*)(WcT + (HDIM+hi)*(2*NXV));
    const v2f* wxn = (const v2f*)(WcT + (2*HDIM+hi)*(2*NXV));
    v2f dr = {0.f,0.f}, dz = {0.f,0.f}, dni = {0.f,0.f}, dnh = {0.f,0.f};
    #pragma unroll
    for (int f = 0; f < NXV; f++){
      dr  = __builtin_elementwise_fma(xv2[f], wxr[f], dr);
      dz  = __builtin_elementwise_fma(xv2[f], wxz[f], dz);
      dni = __builtin_elementwise_fma(xv2[f], wxn[f], dni);
    }
    const v2f* wr = (const v2f*)(Whh + hi*HDIM);
    const v2f* wz = (const v2f*)(Whh + (HDIM+hi)*HDIM);
    const v2f* wn = (const v2f*)(Whh + (2*HDIM+hi)*HDIM);
    #pragma unroll
    for (int k = 0; k < 32; k++){
      dr  = __builtin_elementwise_fma(h2[k], wr[k], dr);
      dz  = __builtin_elementwise_fma(h2[k], wz[k], dz);
      dnh = __builtin_elementwise_fma(h2[k], wn[k], dnh);
    }
    float r = sigm(brz[hi]      + dr.x + dr.y);
    float z = sigm(brz[HDIM+hi] + dz.x + dz.y);
    float n = tanh_f(bni[hi] + dni.x + dni.y + r*(bnh[hi] + dnh.x + dnh.y));
    float hold = lds[hi][lane];            // == old h[hi], avoids dynamic reg index
    lds[hi][lane] = (1.f - z)*n + z*hold;
  }
  __syncthreads();
  #pragma unroll
  for (int k = 0; k < 32; k++){ h2[k].x = lds[2*k][lane]; h2[k].y = lds[2*k+1][lane]; }
  __syncthreads();
}

__global__ __launch_bounds__(64) void model_kernel(
    const float* __restrict__ x,
    const float* __restrict__ ws,
    const float* __restrict__ enc_Whh, const float* __restrict__ enc_bhh,
    const float* __restrict__ dec_Whh, const float* __restrict__ dec_bhh,
    const float* __restrict__ embed_b,
    const float* __restrict__ gat_att_src, const float* __restrict__ gat_att_dst,
    const float* __restrict__ gat_b,
    const float* __restrict__ out_b1, const float* __restrict__ out_W2, const float* __restrict__ out_b2,
    const float* __restrict__ conf_b1, const float* __restrict__ conf_W2, const float* __restrict__ conf_b2,
    float* __restrict__ traj_out, float* __restrict__ conf_out,
    int B)
{
  __shared__ float lds[HDIM][64];   // transposed [idx][lane]: conflict-free everywhere
  const int lane = threadIdx.x;
  const int sl = lane / 5;
  const int nl = lane - sl*5;
  const int samp = blockIdx.x*SPW + sl;
  const bool active = (lane < ACT) && (samp < B);
  const int sc = (samp < B) ? samp : (B-1);
  const float* xb = x + (size_t)sc*(TIN*NNODE*FD) + nl*FD;

  const float* WcET  = ws;
  const float* bcE   = ws + 1920;
  const float* WcDT  = ws + 2112;
  const float* bcD   = ws + 2496;
  const float* W1T   = ws + 2688;
  const float* cW1T  = ws + 6784;
  const float* gWT   = ws + 10880;
  const float* embWT = ws + 14976;
  const float* brzE  = ws + 15616;
  const float* brzD  = ws + 15744;

  v2f h2[32];
  #pragma unroll
  for (int k = 0; k < 32; k++){ h2[k] = (v2f){0.f,0.f}; }
  #pragma unroll
  for (int k = 0; k < HDIM; k++) lds[k][lane] = 0.f;
  __syncthreads();

  // ---------------- GRU encoder (5 steps) ----------------
  for (int t = 0; t < TIN; t++){
    v2f xv2[5];
    const float* xt = xb + t*(NNODE*FD);
    #pragma unroll
    for (int f = 0; f < 5; f++){ float2 v = *(const float2*)(xt+2*f); xv2[f] = (v2f){v.x, v.y}; }
    gru_step<5>(h2, xv2, WcET, brzE, bcE+2*HDIM, enc_bhh+2*HDIM, enc_Whh, lane, lds);
  }

  // ---------------- GAT on last frame ----------------
  v2f xv2[5];
  {
    const float* xt = xb + (TIN-1)*(NNODE*FD);
    #pragma unroll
    for (int f = 0; f < 5; f++){ float2 v = *(const float2*)(xt+2*f); xv2[f] = (v2f){v.x, v.y}; }
  }
  float msum = xv2[0].x + xv2[0].y + xv2[1].x + xv2[1].y + xv2[2].x + xv2[2].y;
  const float maskf = (msum != 0.f) ? 1.f : 0.f;

  float emb[HDIM];                         // x_emb last frame (real embed, not folded)
  for (int e = 0; e < HDIM; e++){
    v2f a = {0.f,0.f};
    const v2f* we = (const v2f*)(embWT + e*FD);
    #pragma unroll
    for (int f = 0; f < 5; f++) a = __builtin_elementwise_fma(xv2[f], we[f], a);
    emb[e] = embed_b[e] + a.x + a.y;
  }

  float asum = 0.f, adsum = 0.f;
  for (int r = 0; r < HDIM; r++){          // xl = emb @ gat_W  -> lds; + attention dots
    const v2f* wg = (const v2f*)(gWT + r*HDIM);
    v2f a = {0.f,0.f};
    #pragma unroll
    for (int j = 0; j < 32; j++){
      v2f e2 = { emb[2*j], emb[2*j+1] };
      a = __builtin_elementwise_fma(e2, wg[j], a);
    }
    float s = a.x + a.y;
    lds[r][lane] = s;
    asum  += s*gat_att_src[r];
    adsum += s*gat_att_dst[r];
  }
  __syncthreads();                         // cross-lane exchange below

  const int base = ((sl <= 11) ? sl : 11)*5;   // clamp idle lanes in-bounds
  float as_i[5], mk_i[5];
  #pragma unroll
  for (int i = 0; i < 5; i++){
    as_i[i] = __shfl(asum,  base+i, 64);
    mk_i[i] = __shfl(maskf, base+i, 64);
  }
  float mx = -1e30f; float al[5];
  #pragma unroll
  for (int i = 0; i < 5; i++){
    float a = as_i[i] + adsum;
    a = (a > 0.f) ? a : 0.2f*a;                       // leaky_relu 0.2
    bool valid = (i == nl) || (mk_i[i] != 0.f && maskf != 0.f);
    al[i] = valid ? a : -1e30f;
    mx = fmaxf(mx, al[i]);
  }
  float w5[5]; float esum = 0.f;
  #pragma unroll
  for (int i = 0; i < 5; i++){
    float e = (al[i] > -1e29f) ? __expf(al[i]-mx) : 0.f;
    w5[i] = e; esum += e;
  }
  const float rs = fastrcp(esum);
  #pragma unroll
  for (int i = 0; i < 5; i++) w5[i] *= rs;

  #pragma unroll
  for (int j = 0; j < 32; j++){                        // h_final = h_enc + gat_out
    float a0 = gat_b[2*j], a1 = gat_b[2*j+1];
    #pragma unroll
    for (int i = 0; i < 5; i++){
      a0 += w5[i]*lds[2*j  ][base+i];
      a1 += w5[i]*lds[2*j+1][base+i];
    }
    h2[j].x += a0; h2[j].y += a1;
  }
  __syncthreads();                                     // all neighbor reads done
  #pragma unroll
  for (int j = 0; j < 32; j++){ lds[2*j][lane] = h2[j].x; lds[2*j+1][lane] = h2[j].y; }
  __syncthreads();

  // ---------------- confidence head ----------------
  float lg[NMODE];
  #pragma unroll
  for (int m = 0; m < NMODE; m++) lg[m] = conf_b2[m];
  for (int ci = 0; ci < HDIM; ci++){
    const v2f* wc = (const v2f*)(cW1T + ci*HDIM);
    v2f a = {0.f,0.f};
    #pragma unroll
    for (int k = 0; k < 32; k++) a = __builtin_elementwise_fma(h2[k], wc[k], a);
    float s = fmaxf(conf_b1[ci] + a.x + a.y, 0.f);
    #pragma unroll
    for (int m = 0; m < NMODE; m++) lg[m] += s*conf_W2[ci*NMODE+m];
  }
  float cm = lg[0];
  #pragma unroll
  for (int m = 1; m < NMODE; m++) cm = fmaxf(cm, lg[m]);
  float ce = 0.f;
  #pragma unroll
  for (int m = 0; m < NMODE; m++){ lg[m] = __expf(lg[m]-cm); ce += lg[m]; }
  const float rc = fastrcp(ce);
  if (active){
    #pragma unroll
    for (int m = 0; m < NMODE; m++)
      conf_out[((size_t)samp*NMODE + m)*NNODE + nl] = lg[m]*rc;
  }

  // ---------------- GRUCell decoder (6 steps) ----------------
  v2f xy[1] = { (v2f){ xv2[0].x, xv2[0].y } };         // x[:, -1, :, 0:2]
  for (int t = 0; t < TOUT; t++){
    gru_step<1>(h2, xy, WcDT, brzD, bcD+2*HDIM, dec_bhh+2*HDIM, dec_Whh, lane, lds);

    v2f o2[5];
    #pragma unroll
    for (int j = 0; j < 5; j++){ o2[j] = (v2f){ out_b2[2*j], out_b2[2*j+1] }; }
    for (int ai = 0; ai < HDIM; ai++){
      const v2f* w1 = (const v2f*)(W1T + ai*HDIM);
      v2f a = {0.f,0.f};
      #pragma unroll
      for (int k = 0; k < 32; k++) a = __builtin_elementwise_fma(h2[k], w1[k], a);
      float s = fmaxf(out_b1[ai] + a.x + a.y, 0.f);
      v2f sv = { s, s };
      const v2f* w2 = (const v2f*)(out_W2 + ai*10);
      #pragma unroll
      for (int j = 0; j < 5; j++) o2[j] = __builtin_elementwise_fma(sv, w2[j], o2[j]);
    }
    float o[10];
    #pragma unroll
    for (int j = 0; j < 5; j++){ o[2*j] = o2[j].x; o[2*j+1] = o2[j].y; }
    if (active){
      #pragma unroll
      for (int m = 0; m < NMODE; m++){
        float2 st = { o[m], o[NMODE+m] };              // (x=o[..,0,m], y=o[..,1,m])
        *(float2*)&traj_out[(((size_t)samp*NMODE + m)*NNODE + nl)*(TOUT*2) + t*2] = st;
      }
    }
    xy[0] = (v2f){ o[0], o[NMODE] };                   // mode-0 xy fed back
  }
}

extern "C" void kernel_launch(void* const* d_in, const int* in_sizes, int n_in,
                              void* d_out, int out_size, void* d_ws, size_t ws_size,
                              hipStream_t stream)
{
  const float* x           = (const float*)d_in[0];
  const float* embed_W     = (const float*)d_in[1];
  const float* embed_b     = (const float*)d_in[2];
  const float* gat_W       = (const float*)d_in[3];
  const float* gat_att_src = (const float*)d_in[4];
  const float* gat_att_dst = (const float*)d_in[5];
  const float* gat_b       = (const float*)d_in[6];
  const float* enc_Wih     = (const float*)d_in[7];
  const float* enc_Whh     = (const float*)d_in[8];
  const float* enc_bih     = (const float*)d_in[9];
  const float* enc_bhh     = (const float*)d_in[10];
  const float* dec_Wih     = (const float*)d_in[11];
  const float* dec_Whh     = (const float*)d_in[12];
  const float* dec_bih     = (const float*)d_in[13];
  const float* dec_bhh     = (const float*)d_in[14];
  const float* out_W1      = (const float*)d_in[15];
  const float* out_b1      = (const float*)d_in[16];
  const float* out_W2      = (const float*)d_in[17];
  const float* out_b2      = (const float*)d_in[18];
  const float* proj_W      = (const float*)d_in[19];
  const float* proj_b      = (const float*)d_in[20];
  const float* conf_W1     = (const float*)d_in[21];
  const float* conf_b1     = (const float*)d_in[22];
  const float* conf_W2     = (const float*)d_in[23];
  const float* conf_b2     = (const float*)d_in[24];

  const int B = in_sizes[0] / (TIN*NNODE*FD);
  float* ws = (float*)d_ws;
  float* traj = (float*)d_out;
  float* conf = traj + (size_t)B*NMODE*NNODE*TOUT*2;

  setup_kernel<<<1, 256, 0, stream>>>(embed_W, embed_b, enc_Wih, enc_bih, dec_Wih, dec_bih,
                                      proj_W, proj_b, out_W1, conf_W1, gat_W,
                                      enc_bhh, dec_bhh, ws);

  const int blocks = (B + SPW - 1) / SPW;
  model_kernel<<<blocks, 64, 0, stream>>>(x, ws,
      enc_Whh, enc_bhh, dec_Whh, dec_bhh,
      embed_b, gat_att_src, gat_att_dst, gat_b,
      out_b1, out_W2, out_b2, conf_b1, conf_W2, conf_b2,
      traj, conf, B);
}

// Round 5
// 396.283 us; speedup vs baseline: 8.3618x; 4.9181x over previous
//
#include <hip/hip_runtime.h>

#define HDIM 64
#define NMODE 5
#define TOUT 6
#define TIN 5
#define NNODE 5
#define FD 10

typedef short bf16x8 __attribute__((ext_vector_type(8)));
typedef float f32x4 __attribute__((ext_vector_type(4)));

#define MFMA16(A,B,C) __builtin_amdgcn_mfma_f32_16x16x32_bf16((A),(B),(C),0,0,0)

// ---------------- ws layout ----------------
// bf16 (short) fragment region, short-index offsets:
//   B1E @ 0      len 18432  (NT=12, KT=3)  enc: [Whh | WcET | brz/bhh-const] cols 0..191
//   B2E @ 18432  len 2048   (NT=4,  KT=1)  enc n-gate x-part (cols 128..191, kt2 rows)
//   B1D @ 20480  len 18432  dec
//   B2D @ 38912  len 2048
//   B3  @ 40960  len 2560   (NT=5,  KT=1)  GAT fold: xl cols 0..63 (+gat_b), col64=a_s, col65=a_d
//   BW1 @ 43520  len 4096   (NT=4,  KT=2)  out_W1
//   BW2 @ 47616  len 1024   (NT=1,  KT=2)  out_W2 (cols 0..9)
//   BC1 @ 48640  len 4096   conf_W1
//   BC2 @ 52736  len 1024   conf_W2 (cols 0..4)
// f32 scratch at float-index 26880 (byte 107520):
//   WcET 0(1920) WcDT 1920(384) bcE 2304 bcD 2496 brzE 2688 brzD 2816
//   EG 2944(640) ebg0 3584 egs 3648 egd 3658 c64/c65 3668
// Fragment element order: ((nt*KT+kt)*64 + lane)*8 + j ; value B[k][n] with
// k = kt*32 + (lane>>4)*8 + j, n = nt*16 + (lane&15).  A built with the SAME
// (lane,j)->k map, so any intra-K permutation cancels between A and B.

__device__ __forceinline__ float fastrcp(float x){ return __builtin_amdgcn_rcpf(x); }
__device__ __forceinline__ float sigm(float x){ return fastrcp(1.f + __expf(-x)); }
__device__ __forceinline__ float tanh_f(float x){ return 2.f*fastrcp(1.f + __expf(-2.f*x)) - 1.f; }

__device__ __forceinline__ short f2b(float f){            // f32 -> bf16 RNE
  unsigned u = __float_as_uint(f);
  unsigned r = (u + 0x7FFFu + ((u >> 16) & 1u)) >> 16;
  return (short)r;
}
__device__ __forceinline__ float b2f(short s){
  return __uint_as_float(((unsigned)(unsigned short)s) << 16);
}
// swizzled LDS index for 64x64 bf16 tile: breaks the 32-way conflict on b128 reads
__device__ __forceinline__ int hswz(int row, int col){
  return row*64 + ((((col>>3) ^ (row&7)))<<3) + (col&7);
}

__global__ void setup_kernel(
    const float* __restrict__ embed_W, const float* __restrict__ embed_b,
    const float* __restrict__ enc_Wih, const float* __restrict__ enc_bih,
    const float* __restrict__ enc_Whh, const float* __restrict__ enc_bhh,
    const float* __restrict__ dec_Wih, const float* __restrict__ dec_bih,
    const float* __restrict__ dec_Whh, const float* __restrict__ dec_bhh,
    const float* __restrict__ proj_W,  const float* __restrict__ proj_b,
    const float* __restrict__ gat_W,   const float* __restrict__ gat_as,
    const float* __restrict__ gat_ad,  const float* __restrict__ gat_b,
    const float* __restrict__ out_W1,  const float* __restrict__ out_W2,
    const float* __restrict__ conf_W1, const float* __restrict__ conf_W2,
    short* __restrict__ wsb)
{
  float* wsf  = (float*)(wsb) + 26880;
  float* WcET = wsf;        float* WcDT = wsf+1920;
  float* bcE  = wsf+2304;   float* bcD  = wsf+2496;
  float* brzE = wsf+2688;   float* brzD = wsf+2816;
  float* EG   = wsf+2944;   float* ebg0 = wsf+3584;
  float* egs  = wsf+3648;   float* egd  = wsf+3658;
  float* c6   = wsf+3668;
  const int t = threadIdx.x;

  for (int i = t; i < 1920; i += 256){ int n=i/10, f=i%10; float s=0.f;
    for(int e=0;e<64;e++) s += embed_W[f*64+e]*enc_Wih[n*64+e]; WcET[i]=s; }
  for (int i = t; i < 384; i += 256){ int n=i/2, c=i%2; float s=0.f;
    for(int e=0;e<64;e++) s += proj_W[c*64+e]*dec_Wih[n*64+e]; WcDT[i]=s; }
  for (int n = t; n < 192; n += 256){
    float s=enc_bih[n]; for(int e=0;e<64;e++) s += embed_b[e]*enc_Wih[n*64+e]; bcE[n]=s;
    float d=dec_bih[n]; for(int e=0;e<64;e++) d += proj_b[e]*dec_Wih[n*64+e]; bcD[n]=d; }
  for (int i = t; i < 640; i += 256){ int f=i/64, n=i%64; float s=0.f;
    for(int e=0;e<64;e++) s += embed_W[f*64+e]*gat_W[e*64+n]; EG[i]=s; }
  for (int n = t; n < 64; n += 256){ float s=0.f;
    for(int e=0;e<64;e++) s += embed_b[e]*gat_W[e*64+n]; ebg0[n]=s; }
  __syncthreads();
  for (int n = t; n < 128; n += 256){ brzE[n]=bcE[n]+enc_bhh[n]; brzD[n]=bcD[n]+dec_bhh[n]; }
  for (int f = t; f < 10; f += 256){ float s=0.f, d=0.f;
    for(int n=0;n<64;n++){ s += EG[f*64+n]*gat_as[n]; d += EG[f*64+n]*gat_ad[n]; }
    egs[f]=s; egd[f]=d; }
  if (t == 0){ float s=0.f, d=0.f;
    for(int n=0;n<64;n++){ s += ebg0[n]*gat_as[n]; d += ebg0[n]*gat_ad[n]; }
    c6[0]=s; c6[1]=d; }
  __syncthreads();

  for (int i = t; i < 18432; i += 256){           // B1E
    int nt=i/1536, r=i%1536, kt=r>>9, r2=r&511, lane=r2>>3, j=r2&7;
    int k=kt*32+(lane>>4)*8+j, n=nt*16+(lane&15);
    float v=0.f;
    if (k < 64) v = enc_Whh[n*64+k];
    else if (k < 74){ if (n < 128) v = WcET[n*10+(k-64)]; }
    else if (k == 74) v = (n < 128) ? brzE[n] : enc_bhh[n];
    wsb[i]=f2b(v);
  }
  for (int i = t; i < 2048; i += 256){            // B2E
    int nt=i>>9, r2=i&511, lane=r2>>3, j=r2&7;
    int k=64+(lane>>4)*8+j, n=128+nt*16+(lane&15);
    float v=0.f;
    if (k < 74) v = WcET[n*10+(k-64)];
    else if (k == 74) v = bcE[n];
    wsb[18432+i]=f2b(v);
  }
  for (int i = t; i < 18432; i += 256){           // B1D
    int nt=i/1536, r=i%1536, kt=r>>9, r2=r&511, lane=r2>>3, j=r2&7;
    int k=kt*32+(lane>>4)*8+j, n=nt*16+(lane&15);
    float v=0.f;
    if (k < 64) v = dec_Whh[n*64+k];
    else if (k < 66){ if (n < 128) v = WcDT[n*2+(k-64)]; }
    else if (k == 66) v = (n < 128) ? brzD[n] : dec_bhh[n];
    wsb[20480+i]=f2b(v);
  }
  for (int i = t; i < 2048; i += 256){            // B2D
    int nt=i>>9, r2=i&511, lane=r2>>3, j=r2&7;
    int k=64+(lane>>4)*8+j, n=128+nt*16+(lane&15);
    float v=0.f;
    if (k < 66) v = WcDT[n*2+(k-64)];
    else if (k == 66) v = bcD[n];
    wsb[38912+i]=f2b(v);
  }
  for (int i = t; i < 2560; i += 256){            // B3
    int nt=i>>9, r2=i&511, lane=r2>>3, j=r2&7;
    int k=64+(lane>>4)*8+j, n=nt*16+(lane&15);
    float v=0.f;
    if (k < 74){ int f=k-64;
      if (n < 64) v = EG[f*64+n]; else if (n == 64) v = egs[f]; else if (n == 65) v = egd[f];
    } else if (k == 74){
      if (n < 64) v = ebg0[n]+gat_b[n]; else if (n == 64) v = c6[0]; else if (n == 65) v = c6[1];
    }
    wsb[40960+i]=f2b(v);
  }
  for (int i = t; i < 4096; i += 256){            // BW1 / BC1
    int nt=i>>10, r=i&1023, kt=r>>9, r2=r&511, lane=r2>>3, j=r2&7;
    int k=kt*32+(lane>>4)*8+j, n=nt*16+(lane&15);
    wsb[43520+i]=f2b(out_W1 [k*64+n]);
    wsb[48640+i]=f2b(conf_W1[k*64+n]);
  }
  for (int i = t; i < 1024; i += 256){            // BW2 / BC2
    int kt=i>>9, r2=i&511, lane=r2>>3, j=r2&7;
    int k=kt*32+(lane>>4)*8+j, n=lane&15;
    wsb[47616+i]=f2b(n<10 ? out_W2 [k*10+n] : 0.f);
    wsb[52736+i]=f2b(n<5  ? conf_W2[k*5 +n] : 0.f);
  }
}

// One GRU step on a wave's 16-row tile. hS holds h (bf16, swizzled); hcd holds
// h in C/D layout as f32 (blend path keeps full precision).
__device__ __forceinline__ void gru_mfma_step(const short* Bs, short* hS,
    float (&hcd)[4][4], bf16x8 af2, int wid, int lane)
{
  const int g = lane>>4, l15 = lane&15;
  const int arow = wid*16 + l15;
  const int sw = arow & 7;
  bf16x8 af0 = *(const bf16x8*)&hS[arow*64 + (((0+g) ^ sw)<<3)];
  bf16x8 af1 = *(const bf16x8*)&hS[arow*64 + (((4+g) ^ sw)<<3)];
  f32x4 acc[12];
  #pragma unroll
  for (int nt = 0; nt < 12; nt++){
    f32x4 a = {0.f,0.f,0.f,0.f};
    a = MFMA16(af0, *(const bf16x8*)&Bs[(nt*3+0)*512 + lane*8], a);
    a = MFMA16(af1, *(const bf16x8*)&Bs[(nt*3+1)*512 + lane*8], a);
    a = MFMA16(af2, *(const bf16x8*)&Bs[(nt*3+2)*512 + lane*8], a);
    acc[nt] = a;
  }
  f32x4 accx[4];
  #pragma unroll
  for (int nt = 0; nt < 4; nt++){
    f32x4 a = {0.f,0.f,0.f,0.f};
    accx[nt] = MFMA16(af2, *(const bf16x8*)&Bs[18432 + nt*512 + lane*8], a);
  }
  #pragma unroll
  for (int nt = 0; nt < 4; nt++){
    #pragma unroll
    for (int j = 0; j < 4; j++){
      float r  = sigm(acc[nt][j]);
      float z  = sigm(acc[nt+4][j]);
      float ng = tanh_f(accx[nt][j] + r*acc[nt+8][j]);
      float hn = (1.f - z)*ng + z*hcd[nt][j];
      hcd[nt][j] = hn;
      hS[hswz(wid*16 + 4*g + j, nt*16 + l15)] = f2b(hn);
    }
  }
}

__global__ __launch_bounds__(256, 2) void model_kernel(
    const float* __restrict__ x, const short* __restrict__ wsb,
    const float* __restrict__ out_b1, const float* __restrict__ out_b2,
    const float* __restrict__ conf_b1, const float* __restrict__ conf_b2,
    float* __restrict__ traj, float* __restrict__ conf, int B)
{
  __shared__ __align__(16) short Bs[20480];   // GRU B1+B2 (enc, then dec)
  __shared__ __align__(16) short hS[4096];    // h tile, bf16 swizzled
  __shared__ __align__(16) short sS[4096];    // xl / relu-s overlay
  __shared__ float xyS[128];
  __shared__ float asdS[128];
  __shared__ float maskS[64];

  const int tid = threadIdx.x;
  const int wid = tid>>6, lane = tid&63;
  const int g = lane>>4, l15 = lane&15;
  const int BN = B*NNODE;
  const int br0 = blockIdx.x*60;
  const int arow = wid*16 + l15;
  const short ONE = 0x3F80;

  float b1r[4], cb1r[4];
  #pragma unroll
  for (int nt = 0; nt < 4; nt++){ b1r[nt]=out_b1[nt*16+l15]; cb1r[nt]=conf_b1[nt*16+l15]; }
  const float b2r  = out_b2 [l15<10 ? l15 : 0];
  const float cb2r = conf_b2[l15<5  ? l15 : 0];

  int growA = br0 + arow; if (growA > BN-1) growA = BN-1;
  const float* xrow = x + (size_t)(growA/5)*250 + (growA%5)*10;

  for (int i = tid; i < 2560; i += 256) ((int4*)Bs)[i] = ((const int4*)wsb)[i];
  for (int i = tid; i < 4096; i += 256) hS[i] = 0;
  float hcd[4][4];
  #pragma unroll
  for (int a1=0;a1<4;a1++){
    #pragma unroll
    for (int a2=0;a2<4;a2++) hcd[a1][a2]=0.f;
  }
  __syncthreads();

  // ---------------- GRU encoder ----------------
  for (int t = 0; t < TIN; t++){
    bf16x8 af2 = {0,0,0,0,0,0,0,0};
    if (g == 0){
      const float2* p = (const float2*)(xrow + t*50);
      float2 v0=p[0], v1=p[1], v2=p[2], v3=p[3];
      af2[0]=f2b(v0.x); af2[1]=f2b(v0.y); af2[2]=f2b(v1.x); af2[3]=f2b(v1.y);
      af2[4]=f2b(v2.x); af2[5]=f2b(v2.y); af2[6]=f2b(v3.x); af2[7]=f2b(v3.y);
    } else if (g == 1){
      const float2* p = (const float2*)(xrow + t*50 + 8);
      float2 v4=p[0];
      af2[0]=f2b(v4.x); af2[1]=f2b(v4.y); af2[2]=ONE;
    }
    gru_mfma_step(Bs, hS, hcd, af2, wid, lane);
    __syncthreads();
  }

  // ---------------- GAT ----------------
  {
    bf16x8 af2 = {0,0,0,0,0,0,0,0};
    if (g == 0){
      const float2* p = (const float2*)(xrow + 4*50);
      float2 v0=p[0], v1=p[1], v2=p[2], v3=p[3];
      af2[0]=f2b(v0.x); af2[1]=f2b(v0.y); af2[2]=f2b(v1.x); af2[3]=f2b(v1.y);
      af2[4]=f2b(v2.x); af2[5]=f2b(v2.y); af2[6]=f2b(v3.x); af2[7]=f2b(v3.y);
      float msum = v0.x+v0.y+v1.x+v1.y+v2.x+v2.y;
      maskS[arow] = (msum != 0.f) ? 1.f : 0.f;
      xyS[arow*2]   = v0.x;                   // dec_in = x[:, -1, :, 0:2]
      xyS[arow*2+1] = v0.y;
    } else if (g == 1){
      const float2* p = (const float2*)(xrow + 4*50 + 8);
      float2 v4=p[0];
      af2[0]=f2b(v4.x); af2[1]=f2b(v4.y); af2[2]=ONE;
    }
    #pragma unroll
    for (int nt = 0; nt < 5; nt++){
      f32x4 a = {0.f,0.f,0.f,0.f};
      a = MFMA16(af2, *(const bf16x8*)(wsb + 40960 + nt*512 + lane*8), a);
      if (nt < 4){
        #pragma unroll
        for (int j = 0; j < 4; j++)
          sS[(wid*16 + 4*g + j)*64 + nt*16 + l15] = f2b(a[j]);   // xl plain layout
      } else if (l15 < 2){
        #pragma unroll
        for (int j = 0; j < 4; j++)
          asdS[(wid*16 + 4*g + j)*2 + l15] = a[j];               // a_s / a_d
      }
    }
  }
  __syncthreads();
  {   // aggregation: 4 threads per dst row, 16 cols each
    int dst = tid >> 2, cb = tid & 3;
    if (dst < 60){
      int nd = dst % 5, bas = dst - nd;
      float ad  = asdS[dst*2+1];
      float mkD = maskS[dst];
      float al[5], mx = -1e30f;
      #pragma unroll
      for (int i = 0; i < 5; i++){
        float a = asdS[(bas+i)*2] + ad;
        a = (a > 0.f) ? a : 0.2f*a;
        bool valid = (i == nd) || (maskS[bas+i] != 0.f && mkD != 0.f);
        al[i] = valid ? a : -1e30f;
        mx = fmaxf(mx, al[i]);
      }
      float w5[5], es = 0.f;
      #pragma unroll
      for (int i = 0; i < 5; i++){ float e = (al[i] > -1e29f) ? __expf(al[i]-mx) : 0.f; w5[i]=e; es+=e; }
      float rs = fastrcp(es);
      #pragma unroll
      for (int i = 0; i < 5; i++) w5[i] *= rs;
      for (int cc = 0; cc < 16; cc++){
        int c = cb*16 + cc;
        float agg = 0.f;
        #pragma unroll
        for (int i = 0; i < 5; i++) agg += w5[i]*b2f(sS[(bas+i)*64 + c]);
        int hi = hswz(dst, c);
        hS[hi] = f2b(b2f(hS[hi]) + agg);       // h_final = h_enc + gat_out
      }
    }
  }
  __syncthreads();
  #pragma unroll
  for (int nt = 0; nt < 4; nt++){
    #pragma unroll
    for (int j = 0; j < 4; j++)
      hcd[nt][j] = b2f(hS[hswz(wid*16+4*g+j, nt*16+l15)]);
  }

  // ---------------- confidence head ----------------
  {
    const int sw = arow & 7;
    bf16x8 hf0 = *(const bf16x8*)&hS[arow*64 + (((0+g) ^ sw)<<3)];
    bf16x8 hf1 = *(const bf16x8*)&hS[arow*64 + (((4+g) ^ sw)<<3)];
    #pragma unroll
    for (int nt = 0; nt < 4; nt++){
      f32x4 a = {0.f,0.f,0.f,0.f};
      a = MFMA16(hf0, *(const bf16x8*)(wsb + 48640 + (nt*2+0)*512 + lane*8), a);
      a = MFMA16(hf1, *(const bf16x8*)(wsb + 48640 + (nt*2+1)*512 + lane*8), a);
      #pragma unroll
      for (int j = 0; j < 4; j++)
        sS[hswz(wid*16+4*g+j, nt*16+l15)] = f2b(fmaxf(a[j] + cb1r[nt], 0.f));
    }
    __syncthreads();
    bf16x8 sf0 = *(const bf16x8*)&sS[arow*64 + (((0+g) ^ sw)<<3)];
    bf16x8 sf1 = *(const bf16x8*)&sS[arow*64 + (((4+g) ^ sw)<<3)];
    f32x4 a = {0.f,0.f,0.f,0.f};
    a = MFMA16(sf0, *(const bf16x8*)(wsb + 52736 + 0*512 + lane*8), a);
    a = MFMA16(sf1, *(const bf16x8*)(wsb + 52736 + 1*512 + lane*8), a);
    #pragma unroll
    for (int j = 0; j < 4; j++){
      float my = a[j] + cb2r;
      float v0 = __shfl(my, (lane&48)+0, 64);
      float v1 = __shfl(my, (lane&48)+1, 64);
      float v2 = __shfl(my, (lane&48)+2, 64);
      float v3 = __shfl(my, (lane&48)+3, 64);
      float v4 = __shfl(my, (lane&48)+4, 64);
      float mx = fmaxf(fmaxf(fmaxf(v0,v1),fmaxf(v2,v3)),v4);
      float es = __expf(v0-mx)+__expf(v1-mx)+__expf(v2-mx)+__expf(v3-mx)+__expf(v4-mx);
      int lrow = wid*16 + 4*g + j;
      int gr = br0 + lrow;
      if (l15 < 5 && lrow < 60 && gr < BN){
        int samp = gr/5, node = gr - samp*5;
        conf[((size_t)samp*NMODE + l15)*NNODE + node] = __expf(my-mx)*fastrcp(es);
      }
    }
    __syncthreads();
  }

  // ---------------- reload decoder B ----------------
  for (int i = tid; i < 2560; i += 256) ((int4*)Bs)[i] = ((const int4*)(wsb + 20480))[i];
  __syncthreads();

  // ---------------- GRUCell decoder ----------------
  for (int t = 0; t < TOUT; t++){
    bf16x8 af2 = {0,0,0,0,0,0,0,0};
    if (g == 0){
      af2[0] = f2b(xyS[arow*2]);
      af2[1] = f2b(xyS[arow*2+1]);
      af2[2] = ONE;
    }
    gru_mfma_step(Bs, hS, hcd, af2, wid, lane);
    __syncthreads();

    const int sw = arow & 7;
    bf16x8 hf0 = *(const bf16x8*)&hS[arow*64 + (((0+g) ^ sw)<<3)];
    bf16x8 hf1 = *(const bf16x8*)&hS[arow*64 + (((4+g) ^ sw)<<3)];
    #pragma unroll
    for (int nt = 0; nt < 4; nt++){
      f32x4 a = {0.f,0.f,0.f,0.f};
      a = MFMA16(hf0, *(const bf16x8*)(wsb + 43520 + (nt*2+0)*512 + lane*8), a);
      a = MFMA16(hf1, *(const bf16x8*)(wsb + 43520 + (nt*2+1)*512 + lane*8), a);
      #pragma unroll
      for (int j = 0; j < 4; j++)
        sS[hswz(wid*16+4*g+j, nt*16+l15)] = f2b(fmaxf(a[j] + b1r[nt], 0.f));
    }
    __syncthreads();
    bf16x8 sf0 = *(const bf16x8*)&sS[arow*64 + (((0+g) ^ sw)<<3)];
    bf16x8 sf1 = *(const bf16x8*)&sS[arow*64 + (((4+g) ^ sw)<<3)];
    f32x4 oo = {0.f,0.f,0.f,0.f};
    oo = MFMA16(sf0, *(const bf16x8*)(wsb + 47616 + 0*512 + lane*8), oo);
    oo = MFMA16(sf1, *(const bf16x8*)(wsb + 47616 + 1*512 + lane*8), oo);
    #pragma unroll
    for (int j = 0; j < 4; j++){
      float ov = oo[j] + b2r;
      int lrow = wid*16 + 4*g + j;
      int gr = br0 + lrow;
      if (l15 < 10 && lrow < 60 && gr < BN){
        int samp = gr/5, node = gr - samp*5;
        int cc = (l15 >= 5) ? 1 : 0;
        int m = l15 - 5*cc;
        traj[((size_t)(samp*NMODE + m)*NNODE + node)*(TOUT*2) + t*2 + cc] = ov;
      }
      if (l15 == 0) xyS[lrow*2]   = ov;    // mode-0 x fed back
      if (l15 == 5) xyS[lrow*2+1] = ov;    // mode-0 y fed back
    }
    __syncthreads();
  }
}

extern "C" void kernel_launch(void* const* d_in, const int* in_sizes, int n_in,
                              void* d_out, int out_size, void* d_ws, size_t ws_size,
                              hipStream_t stream)
{
  const float* x           = (const float*)d_in[0];
  const float* embed_W     = (const float*)d_in[1];
  const float* embed_b     = (const float*)d_in[2];
  const float* gat_W       = (const float*)d_in[3];
  const float* gat_att_src = (const float*)d_in[4];
  const float* gat_att_dst = (const float*)d_in[5];
  const float* gat_b       = (const float*)d_in[6];
  const float* enc_Wih     = (const float*)d_in[7];
  const float* enc_Whh     = (const float*)d_in[8];
  const float* enc_bih     = (const float*)d_in[9];
  const float* enc_bhh     = (const float*)d_in[10];
  const float* dec_Wih     = (const float*)d_in[11];
  const float* dec_Whh     = (const float*)d_in[12];
  const float* dec_bih     = (const float*)d_in[13];
  const float* dec_bhh     = (const float*)d_in[14];
  const float* out_W1      = (const float*)d_in[15];
  const float* out_b1      = (const float*)d_in[16];
  const float* out_W2      = (const float*)d_in[17];
  const float* out_b2      = (const float*)d_in[18];
  const float* proj_W      = (const float*)d_in[19];
  const float* proj_b      = (const float*)d_in[20];
  const float* conf_W1     = (const float*)d_in[21];
  const float* conf_b1     = (const float*)d_in[22];
  const float* conf_W2     = (const float*)d_in[23];
  const float* conf_b2     = (const float*)d_in[24];

  const int B = in_sizes[0] / (TIN*NNODE*FD);
  const int BN = B*NNODE;
  short* wsb = (short*)d_ws;
  float* traj = (float*)d_out;
  float* conf = traj + (size_t)B*NMODE*NNODE*TOUT*2;

  setup_kernel<<<1, 256, 0, stream>>>(embed_W, embed_b, enc_Wih, enc_bih, enc_Whh, enc_bhh,
                                      dec_Wih, dec_bih, dec_Whh, dec_bhh, proj_W, proj_b,
                                      gat_W, gat_att_src, gat_att_dst, gat_b,
                                      out_W1, out_W2, conf_W1, conf_W2, wsb);

  const int blocks = (BN + 59)/60;
  model_kernel<<<blocks, 256, 0, stream>>>(x, wsb, out_b1, out_b2, conf_b1, conf_b2,
                                           traj, conf, B);
}